// Round 9
// baseline (250.940 us; speedup 1.0000x reference)
//
#include <hip/hip_runtime.h>
#include <math.h>

#define NN 20000
#define KK 16
#define DD 256
#define VV 64
#define SAS 336  // LDS A-tile row stride in bf16 elems (320 data + 16 pad)

typedef __attribute__((ext_vector_type(8))) __bf16 bf16x8;
typedef __attribute__((ext_vector_type(4))) float floatx4;
typedef __attribute__((ext_vector_type(2))) float floatx2;
typedef __attribute__((ext_vector_type(8))) unsigned short ushort8;
typedef __attribute__((ext_vector_type(4))) unsigned int uint4v;
typedef __attribute__((ext_vector_type(2))) unsigned int uint2v;

__device__ __forceinline__ float4 ld4(const float* p) { return *reinterpret_cast<const float4*>(p); }

__device__ __forceinline__ unsigned short f2bf(float f) {
    union { float f; unsigned u; } v; v.f = f;
    unsigned r = v.u + 0x7FFFu + ((v.u >> 16) & 1u);
    return (unsigned short)(r >> 16);
}
__device__ __forceinline__ float bf2f(unsigned short u) {
    union { unsigned u; float f; } v; v.u = ((unsigned)u) << 16;
    return v.f;
}
__device__ __forceinline__ unsigned char f2q(float f) {  // fp8 e4m3, RTNE
    return (unsigned char)(__builtin_amdgcn_cvt_pk_fp8_f32(f, 0.f, 0u, false) & 0xFFu);
}
__device__ __forceinline__ float q2f(unsigned char q) {
    floatx2 r = __builtin_amdgcn_cvt_pk_f32_fp8((unsigned)q, false);
    return r.x;
}
__device__ __forceinline__ float ftanh(float v) {
    float e = __expf(2.f * v);
    return 1.f - 2.f * __builtin_amdgcn_rcpf(e + 1.f);
}

// Merged setup: blocks 0..119 pack U1/U23 (bf16 B-fragments, EW folded inline);
// blocks 120..5119: edge-histogram -> Sb cols [256,320) and x -> bf16 (xh).
__global__ __launch_bounds__(256) void setup(
    const int* __restrict__ ie, const float* __restrict__ im,
    const int* __restrict__ oe, const float* __restrict__ om,
    const float* __restrict__ x,
    const float* __restrict__ e1, const float* __restrict__ W1,
    const float* __restrict__ e2, const float* __restrict__ W2,
    const float* __restrict__ e3, const float* __restrict__ W3,
    unsigned short* __restrict__ U1, unsigned short* __restrict__ U23,
    unsigned short* __restrict__ Sb, unsigned short* __restrict__ xh) {
    int blk = blockIdx.x, tid = threadIdx.x;
    if (blk < 120) {
        int u1path = blk < 40;
        int NT = u1path ? 16 : 32;
        int g = (u1path ? blk : blk - 40) * 256 + tid;
        int lane = g & 63, ntk = g >> 6;
        int nt = ntk % NT, kt = ntk / NT;
        if (kt >= 10) return;
        int n = nt * 16 + (lane & 15);
        int kbase = kt * 32 + (lane >> 4) * 8;
        const float* W; const float* emb;
        if (u1path)       { W = W1; emb = e1; }
        else if (n < 256) { W = W2; emb = e2; }
        else              { W = W3; emb = e3; n -= 256; }
        float vals[8];
        if (kbase < 256) {
            #pragma unroll
            for (int j = 0; j < 8; ++j) vals[j] = W[(size_t)(kbase + j) * DD + n];
        } else {
            int vb = kbase - 256;
            #pragma unroll
            for (int z = 0; z < 8; ++z) vals[z] = 0.f;
            #pragma unroll 4
            for (int j = 0; j < 256; ++j) {
                float wv = W[(size_t)(256 + j) * DD + n];
                #pragma unroll
                for (int z = 0; z < 8; ++z) vals[z] += emb[(vb + z) * DD + j] * wv;
            }
        }
        unsigned short o8[8];
        #pragma unroll
        for (int j = 0; j < 8; ++j) o8[j] = f2bf(vals[j]);
        unsigned short* U = u1path ? U1 : U23;
        *reinterpret_cast<uint4v*>(&U[(size_t)g * 8]) = *reinterpret_cast<uint4v*>(o8);
    } else {
        int pb = blk - 120;
        int w = tid >> 6, lane = tid & 63;
        int n = pb * 4 + w;
        int e = 0; float m = 0.f;
        if (lane < 16)      { e = ie[n * KK + lane];      m = im[n * KK + lane]; }
        else if (lane < 32) { e = oe[n * KK + lane - 16]; m = om[n * KK + lane - 16]; }
        float h = 0.f;
        #pragma unroll
        for (int j = 0; j < 32; ++j) {
            int ev = __shfl(e, j);
            float mv = __shfl(m, j);
            if (ev == lane) h += mv;
        }
        Sb[(size_t)n * 320 + 256 + lane] = f2bf(h);
        size_t base = (size_t)pb * 1024 + tid * 4;
        float4 v = ld4(x + base);
        ushort4 o; o.x = f2bf(v.x); o.y = f2bf(v.y); o.z = f2bf(v.z); o.w = f2bf(v.w);
        *reinterpret_cast<ushort4*>(xh + base) = o;
    }
}

// L2-resident chunked bf16 gather: chunk = 64 cols (20000*128B = 2.56MB < 4MB XCD L2).
// Wave handles 2 nodes; lane = rowgroup(8) x coloff(8); 8 independent 16B loads.
__global__ __launch_bounds__(256) void aggx(const unsigned short* __restrict__ xh,
                                            const int* __restrict__ ii, const float* __restrict__ im,
                                            const int* __restrict__ oi, const float* __restrict__ om,
                                            unsigned short* __restrict__ Sb) {
    int blk = blockIdx.x;
    int chunk = blk / 2500, nb = blk % 2500;
    int w = threadIdx.x >> 6, lane = threadIdx.x & 63;
    int na = nb * 8 + w * 2, nbod = na + 1;
    int rg = lane >> 3, co = lane & 7;
    const unsigned short* base = xh + chunk * 64 + co * 8;
    float acc[2][8];
    #pragma unroll
    for (int s = 0; s < 2; ++s)
        #pragma unroll
        for (int z = 0; z < 8; ++z) acc[s][z] = 0.f;
    #pragma unroll
    for (int s = 0; s < 2; ++s) {
        int n = s ? nbod : na;
        int i0 = ii[n * KK + rg], i1 = ii[n * KK + rg + 8];
        int i2 = oi[n * KK + rg], i3 = oi[n * KK + rg + 8];
        float m0 = im[n * KK + rg], m1 = im[n * KK + rg + 8];
        float m2 = om[n * KK + rg], m3 = om[n * KK + rg + 8];
        ushort8 u0 = *reinterpret_cast<const ushort8*>(base + (size_t)i0 * DD);
        ushort8 u1 = *reinterpret_cast<const ushort8*>(base + (size_t)i1 * DD);
        ushort8 u2 = *reinterpret_cast<const ushort8*>(base + (size_t)i2 * DD);
        ushort8 u3 = *reinterpret_cast<const ushort8*>(base + (size_t)i3 * DD);
        #pragma unroll
        for (int z = 0; z < 8; ++z)
            acc[s][z] = m0 * bf2f(u0[z]) + m1 * bf2f(u1[z]) + m2 * bf2f(u2[z]) + m3 * bf2f(u3[z]);
    }
    #pragma unroll
    for (int s = 0; s < 2; ++s)
        #pragma unroll
        for (int z = 0; z < 8; ++z) {
            acc[s][z] += __shfl_xor(acc[s][z], 8);
            acc[s][z] += __shfl_xor(acc[s][z], 16);
            acc[s][z] += __shfl_xor(acc[s][z], 32);
        }
    if (rg < 2) {
        int n = rg ? nbod : na;
        unsigned short o8[8];
        #pragma unroll
        for (int z = 0; z < 8; ++z) o8[z] = f2bf(acc[rg][z]);
        __builtin_nontemporal_store(*reinterpret_cast<uint4v*>(o8),
            reinterpret_cast<uint4v*>(&Sb[(size_t)n * 320 + chunk * 64 + co * 8]));
    }
}

// L2-resident chunked fp8 gather of hidden: chunk = 128 cols (2.56MB).
__global__ __launch_bounds__(256) void aggq(const unsigned char* __restrict__ h8,
                                            const int* __restrict__ ii, const float* __restrict__ im,
                                            const int* __restrict__ oi, const float* __restrict__ om,
                                            unsigned short* __restrict__ Sb) {
    int blk = blockIdx.x;
    int chunk = blk / 2500, nb = blk % 2500;
    int w = threadIdx.x >> 6, lane = threadIdx.x & 63;
    int na = nb * 8 + w * 2, nbod = na + 1;
    int rg = lane >> 3, co = lane & 7;
    const unsigned char* base = h8 + chunk * 128 + co * 16;
    float acc[2][16];
    #pragma unroll
    for (int s = 0; s < 2; ++s)
        #pragma unroll
        for (int z = 0; z < 16; ++z) acc[s][z] = 0.f;
    #pragma unroll
    for (int s = 0; s < 2; ++s) {
        int n = s ? nbod : na;
        int idx[4]; float msk[4];
        idx[0] = ii[n * KK + rg]; idx[1] = ii[n * KK + rg + 8];
        idx[2] = oi[n * KK + rg]; idx[3] = oi[n * KK + rg + 8];
        msk[0] = im[n * KK + rg]; msk[1] = im[n * KK + rg + 8];
        msk[2] = om[n * KK + rg]; msk[3] = om[n * KK + rg + 8];
        #pragma unroll
        for (int j = 0; j < 4; ++j) {
            uint4v u = *reinterpret_cast<const uint4v*>(base + (size_t)idx[j] * DD);
            float m = msk[j];
            #pragma unroll
            for (int d = 0; d < 4; ++d) {
                floatx2 f01 = __builtin_amdgcn_cvt_pk_f32_fp8(u[d], false);
                floatx2 f23 = __builtin_amdgcn_cvt_pk_f32_fp8(u[d], true);
                acc[s][d * 4 + 0] += m * f01.x; acc[s][d * 4 + 1] += m * f01.y;
                acc[s][d * 4 + 2] += m * f23.x; acc[s][d * 4 + 3] += m * f23.y;
            }
        }
    }
    #pragma unroll
    for (int s = 0; s < 2; ++s)
        #pragma unroll
        for (int z = 0; z < 16; ++z) {
            acc[s][z] += __shfl_xor(acc[s][z], 8);
            acc[s][z] += __shfl_xor(acc[s][z], 16);
            acc[s][z] += __shfl_xor(acc[s][z], 32);
        }
    if (rg < 2) {
        int n = rg ? nbod : na;
        unsigned short o16[16];
        #pragma unroll
        for (int z = 0; z < 16; ++z) o16[z] = f2bf(acc[rg][z]);
        uint4v* dst = reinterpret_cast<uint4v*>(&Sb[(size_t)n * 320 + chunk * 128 + co * 16]);
        __builtin_nontemporal_store(reinterpret_cast<uint4v*>(o16)[0], dst);
        __builtin_nontemporal_store(reinterpret_cast<uint4v*>(o16)[1], dst + 1);
    }
}

// hidden = x + 2*b1 + [S1|H] @ U1; 32-row tile, wave = 2 Mtiles x 4 Ntiles (B reg-shared).
__global__ __launch_bounds__(256) void mm1(const unsigned short* __restrict__ Sb, const unsigned short* __restrict__ U,
                                           const unsigned short* __restrict__ xh, const float* __restrict__ b,
                                           float* __restrict__ out, unsigned char* __restrict__ h8) {
    __shared__ unsigned short sA[32 * SAS];
    int n0 = blockIdx.x * 32;
    int tid = threadIdx.x;
    #pragma unroll
    for (int q = 0; q < 5; ++q) {
        int c = q * 256 + tid;
        int row = c / 40, k8 = c % 40;
        *reinterpret_cast<uint4v*>(&sA[row * SAS + k8 * 8]) = __builtin_nontemporal_load(
            reinterpret_cast<const uint4v*>(&Sb[(size_t)(n0 + row) * 320 + k8 * 8]));
    }
    __syncthreads();
    int lane = tid & 63, w = tid >> 6;
    int lr = lane & 15, quad = lane >> 4;
    floatx4 z = {0.f, 0.f, 0.f, 0.f};
    floatx4 acc[2][4] = {{z, z, z, z}, {z, z, z, z}};
    for (int kt = 0; kt < 10; ++kt) {
        bf16x8 a0 = *reinterpret_cast<const bf16x8*>(&sA[lr * SAS + kt * 32 + quad * 8]);
        bf16x8 a1 = *reinterpret_cast<const bf16x8*>(&sA[(lr + 16) * SAS + kt * 32 + quad * 8]);
        #pragma unroll
        for (int t = 0; t < 4; ++t) {
            bf16x8 bf = *reinterpret_cast<const bf16x8*>(&U[(size_t)((kt * 16 + w * 4 + t) * 64 + lane) * 8]);
            acc[0][t] = __builtin_amdgcn_mfma_f32_16x16x32_bf16(a0, bf, acc[0][t], 0, 0, 0);
            acc[1][t] = __builtin_amdgcn_mfma_f32_16x16x32_bf16(a1, bf, acc[1][t], 0, 0, 0);
        }
    }
    #pragma unroll
    for (int t = 0; t < 4; ++t) {
        int col = (w * 4 + t) * 16 + lr;
        float bb = 2.f * b[col];
        #pragma unroll
        for (int mt = 0; mt < 2; ++mt) {
            #pragma unroll
            for (int r = 0; r < 4; ++r) {
                size_t o = (size_t)(n0 + mt * 16 + quad * 4 + r) * DD + col;
                float v = bf2f(xh[o]) + bb + acc[mt][t][r];
                __builtin_nontemporal_store(v, out + o);
                h8[o] = f2q(v);
            }
        }
    }
}

// Both mu and logvar matmuls + fast tanh + KLD, 32-row tile.
__global__ __launch_bounds__(256) void mm23(const unsigned short* __restrict__ Sb, const unsigned short* __restrict__ U,
                                            const unsigned char* __restrict__ h8, const float* __restrict__ b2,
                                            const float* __restrict__ b3, float* __restrict__ kld) {
    __shared__ unsigned short sA[32 * SAS];
    __shared__ float red[4];
    int n0 = blockIdx.x * 32;
    int tid = threadIdx.x;
    #pragma unroll
    for (int q = 0; q < 5; ++q) {
        int c = q * 256 + tid;
        int row = c / 40, k8 = c % 40;
        *reinterpret_cast<uint4v*>(&sA[row * SAS + k8 * 8]) = __builtin_nontemporal_load(
            reinterpret_cast<const uint4v*>(&Sb[(size_t)(n0 + row) * 320 + k8 * 8]));
    }
    __syncthreads();
    int lane = tid & 63, w = tid >> 6;
    int lr = lane & 15, quad = lane >> 4;
    floatx4 z = {0.f, 0.f, 0.f, 0.f};
    floatx4 am[2][4] = {{z, z, z, z}, {z, z, z, z}};
    floatx4 al[2][4] = {{z, z, z, z}, {z, z, z, z}};
    for (int kt = 0; kt < 10; ++kt) {
        bf16x8 a0 = *reinterpret_cast<const bf16x8*>(&sA[lr * SAS + kt * 32 + quad * 8]);
        bf16x8 a1 = *reinterpret_cast<const bf16x8*>(&sA[(lr + 16) * SAS + kt * 32 + quad * 8]);
        #pragma unroll
        for (int t = 0; t < 4; ++t) {
            int nt = w * 4 + t;
            bf16x8 bmu = *reinterpret_cast<const bf16x8*>(&U[(size_t)((kt * 32 + nt) * 64 + lane) * 8]);
            bf16x8 blv = *reinterpret_cast<const bf16x8*>(&U[(size_t)((kt * 32 + 16 + nt) * 64 + lane) * 8]);
            am[0][t] = __builtin_amdgcn_mfma_f32_16x16x32_bf16(a0, bmu, am[0][t], 0, 0, 0);
            am[1][t] = __builtin_amdgcn_mfma_f32_16x16x32_bf16(a1, bmu, am[1][t], 0, 0, 0);
            al[0][t] = __builtin_amdgcn_mfma_f32_16x16x32_bf16(a0, blv, al[0][t], 0, 0, 0);
            al[1][t] = __builtin_amdgcn_mfma_f32_16x16x32_bf16(a1, blv, al[1][t], 0, 0, 0);
        }
    }
    float kacc = 0.f;
    #pragma unroll
    for (int t = 0; t < 4; ++t) {
        int col = (w * 4 + t) * 16 + lr;
        float bm = 2.f * b2[col];
        float bl = 2.f * b3[col];
        #pragma unroll
        for (int mt = 0; mt < 2; ++mt) {
            #pragma unroll
            for (int r = 0; r < 4; ++r) {
                float h = q2f(h8[(size_t)(n0 + mt * 16 + quad * 4 + r) * DD + col]);
                float tm = ftanh(h + bm + am[mt][t][r]);
                float tl = ftanh(h + bl + al[mt][t][r]);
                kacc += (1.f - tm * tm) + (2.f * tl - __expf(2.f * tl));
            }
        }
    }
    #pragma unroll
    for (int off = 32; off > 0; off >>= 1) kacc += __shfl_xor(kacc, off);
    if (lane == 0) red[w] = kacc;
    __syncthreads();
    if (tid == 0)
        atomicAdd(kld, (red[0] + red[1] + red[2] + red[3]) * (-0.5f / ((float)NN * (float)NN)));
}

extern "C" void kernel_launch(void* const* d_in, const int* in_sizes, int n_in,
                              void* d_out, int out_size, void* d_ws, size_t ws_size,
                              hipStream_t stream) {
    const float* x  = (const float*)d_in[0];
    const int*   ii = (const int*)d_in[1];
    const int*   ie = (const int*)d_in[2];
    const float* im = (const float*)d_in[3];
    const int*   oi = (const int*)d_in[4];
    const int*   oe = (const int*)d_in[5];
    const float* om = (const float*)d_in[6];
    const float* e1 = (const float*)d_in[7];
    const float* W1 = (const float*)d_in[8];
    const float* b1 = (const float*)d_in[9];
    const float* e2 = (const float*)d_in[10];
    const float* W2 = (const float*)d_in[11];
    const float* b2 = (const float*)d_in[12];
    const float* e3 = (const float*)d_in[13];
    const float* W3 = (const float*)d_in[14];
    const float* b3 = (const float*)d_in[15];
    float* out = (float*)d_out;

    char* ws = (char*)d_ws;
    unsigned short* U1  = (unsigned short*)(ws);             // 163840 B
    unsigned short* U23 = (unsigned short*)(ws + 163840);    // 327680 B
    unsigned short* Sb  = (unsigned short*)(ws + 491520);    // 20000*320 bf16 (12.8 MB)
    unsigned short* xh  = (unsigned short*)(ws + 13291520);  // 20000*256 bf16 (10.24 MB)
    unsigned char*  h8  = (unsigned char*)(ws + 23531520);   // 20000*256 fp8  (5.12 MB)

    (void)hipMemsetAsync(out + (size_t)NN * DD, 0, 4, stream);
    setup<<<120 + NN / 4, 256, 0, stream>>>(ie, im, oe, om, x, e1, W1, e2, W2, e3, W3,
                                            U1, U23, Sb, xh);
    aggx <<<4 * NN / 8, 256, 0, stream>>>(xh, ii, im, oi, om, Sb);
    mm1  <<<NN / 32, 256, 0, stream>>>(Sb, U1, xh, b1, out, h8);
    aggq <<<2 * NN / 8, 256, 0, stream>>>(h8, ii, im, oi, om, Sb);
    mm23 <<<NN / 32, 256, 0, stream>>>(Sb, U23, h8, b2, b3,
                                       out + (size_t)NN * DD);
}

// Round 10
// 192.228 us; speedup vs baseline: 1.3054x; 1.3054x over previous
//
#include <hip/hip_runtime.h>
#include <math.h>

#define NN 20000
#define KK 16
#define DD 256
#define VV 64
#define NT1 16
#define SAS 336      // fmm1/fmm23 A-tile row stride in bf16 elems
#define SAS8 336     // fmm23 fp8 staging not used; kept for clarity

typedef __attribute__((ext_vector_type(8))) __bf16 bf16x8;
typedef __attribute__((ext_vector_type(4))) float floatx4;
typedef __attribute__((ext_vector_type(2))) float floatx2;
typedef __attribute__((ext_vector_type(8))) unsigned short ushort8;
typedef __attribute__((ext_vector_type(4))) unsigned int uint4v;

__device__ __forceinline__ float4 ld4(const float* p) { return *reinterpret_cast<const float4*>(p); }

__device__ __forceinline__ unsigned short f2bf(float f) {
    union { float f; unsigned u; } v; v.f = f;
    unsigned r = v.u + 0x7FFFu + ((v.u >> 16) & 1u);
    return (unsigned short)(r >> 16);
}
__device__ __forceinline__ float bf2f(unsigned short u) {
    union { unsigned u; float f; } v; v.u = ((unsigned)u) << 16;
    return v.f;
}
__device__ __forceinline__ unsigned char f2q(float f) {  // fp8 e4m3, RTNE
    return (unsigned char)(__builtin_amdgcn_cvt_pk_fp8_f32(f, 0.f, 0u, false) & 0xFFu);
}
__device__ __forceinline__ float q2f(unsigned char q) {
    floatx2 r = __builtin_amdgcn_cvt_pk_f32_fp8((unsigned)q, false);
    return r.x;
}
__device__ __forceinline__ float ftanh(float v) {
    float e = __expf(2.f * v);
    return 1.f - 2.f * __builtin_amdgcn_rcpf(e + 1.f);
}

// Launch 1: blocks 0..191 compute EW[layer][v][d] with d=tid (coalesced W reads);
// blocks 192..5191: edge-histogram -> Hc, x -> bf16 (xh), and kld := 0.
__global__ __launch_bounds__(256) void ewhist(
    const int* __restrict__ ie, const float* __restrict__ im,
    const int* __restrict__ oe, const float* __restrict__ om,
    const float* __restrict__ x,
    const float* __restrict__ e1, const float* __restrict__ W1,
    const float* __restrict__ e2, const float* __restrict__ W2,
    const float* __restrict__ e3, const float* __restrict__ W3,
    float* __restrict__ EW, unsigned short* __restrict__ Hc,
    unsigned short* __restrict__ xh, float* __restrict__ kld) {
    int blk = blockIdx.x, tid = threadIdx.x;
    if (blk < 192) {
        int layer = blk >> 6, v = blk & 63, d = tid;
        const float* emb = layer == 0 ? e1 : (layer == 1 ? e2 : e3);
        const float* W   = layer == 0 ? W1 : (layer == 1 ? W2 : W3);
        float acc = 0.f;
        #pragma unroll 8
        for (int j = 0; j < 256; ++j)
            acc += emb[v * DD + j] * W[(size_t)(256 + j) * DD + d];
        EW[(size_t)layer * VV * DD + v * DD + d] = acc;
    } else {
        int pb = blk - 192;
        int w = tid >> 6, lane = tid & 63;
        int n = pb * 4 + w;
        int e = 0; float m = 0.f;
        if (lane < 16)      { e = ie[n * KK + lane];      m = im[n * KK + lane]; }
        else if (lane < 32) { e = oe[n * KK + lane - 16]; m = om[n * KK + lane - 16]; }
        float h = 0.f;
        #pragma unroll
        for (int j = 0; j < 32; ++j) {
            int ev = __shfl(e, j);
            float mv = __shfl(m, j);
            if (ev == lane) h += mv;
        }
        Hc[(size_t)n * 64 + lane] = f2bf(h);
        size_t base = (size_t)pb * 1024 + tid * 4;
        float4 v = ld4(x + base);
        ushort4 o; o.x = f2bf(v.x); o.y = f2bf(v.y); o.z = f2bf(v.z); o.w = f2bf(v.w);
        *reinterpret_cast<ushort4*>(xh + base) = o;
        if (pb == 0 && tid == 0) *kld = 0.f;
    }
}

// Launch 2: pure copy/quantize pack of U1/U23 B-fragments from W and precomputed EW.
__global__ __launch_bounds__(256) void packU(
    const float* __restrict__ W1, const float* __restrict__ W2, const float* __restrict__ W3,
    const float* __restrict__ EW,
    unsigned short* __restrict__ U1, unsigned short* __restrict__ U23) {
    int blk = blockIdx.x, tid = threadIdx.x;
    int u1path = blk < 40;
    int NT = u1path ? 16 : 32;
    int g = (u1path ? blk : blk - 40) * 256 + tid;
    int lane = g & 63, ntk = g >> 6;
    int nt = ntk % NT, kt = ntk / NT;
    if (kt >= 10) return;
    int n = nt * 16 + (lane & 15);
    int kbase = kt * 32 + (lane >> 4) * 8;
    const float* W; const float* EWl;
    if (u1path)       { W = W1; EWl = EW; }
    else if (n < 256) { W = W2; EWl = EW + VV * DD; }
    else              { W = W3; EWl = EW + 2 * VV * DD; n -= 256; }
    unsigned short o8[8];
    #pragma unroll
    for (int j = 0; j < 8; ++j) {
        int k = kbase + j;
        float v = (k < 256) ? W[(size_t)k * DD + n] : EWl[(size_t)(k - 256) * DD + n];
        o8[j] = f2bf(v);
    }
    unsigned short* U = u1path ? U1 : U23;
    *reinterpret_cast<uint4v*>(&U[(size_t)g * 8]) = *reinterpret_cast<uint4v*>(o8);
}

// Fused pass 1 (R5-proven): bf16 gather of x into LDS A-tile, then
// hidden = x + 2*b1 + [S1|H] @ U1. Writes f32 out + fp8 copy for the KLD path.
__global__ __launch_bounds__(256) void fmm1(const unsigned short* __restrict__ xh, const unsigned short* __restrict__ Hc,
                                            const int* __restrict__ ii, const float* __restrict__ im,
                                            const int* __restrict__ oi, const float* __restrict__ om,
                                            const unsigned short* __restrict__ U, const float* __restrict__ b,
                                            float* __restrict__ out, unsigned char* __restrict__ h8) {
    __shared__ unsigned short sA[16 * SAS];
    __shared__ int sidx[16][32];
    __shared__ float smsk[16][32];
    int n0 = blockIdx.x * 16;
    int tid = threadIdx.x;
    for (int q = tid; q < 512; q += 256) {
        int r = q >> 5, j = q & 31;
        int n = n0 + r;
        sidx[r][j] = (j < 16) ? ii[n * KK + j] : oi[n * KK + j - 16];
        smsk[r][j] = (j < 16) ? im[n * KK + j] : om[n * KK + j - 16];
    }
    if (tid < 128) {  // stage H cols [256,320)
        int r = tid >> 3, k8 = tid & 7;
        *reinterpret_cast<uint4v*>(&sA[r * SAS + 256 + k8 * 8]) =
            *reinterpret_cast<const uint4v*>(&Hc[(size_t)(n0 + r) * 64 + k8 * 8]);
    }
    __syncthreads();
    int lane = tid & 63, w = tid >> 6;
    int half = lane >> 5, c = (lane & 31) * 8;
    #pragma unroll
    for (int rr = 0; rr < 4; ++rr) {
        int row = w * 4 + rr;
        float acc[8] = {0.f, 0.f, 0.f, 0.f, 0.f, 0.f, 0.f, 0.f};
        #pragma unroll
        for (int j = 0; j < 16; ++j) {
            int j2 = j * 2 + half;
            int idx = sidx[row][j2];
            float m = smsk[row][j2];
            ushort8 u = *reinterpret_cast<const ushort8*>(xh + (size_t)idx * DD + c);
            #pragma unroll
            for (int z = 0; z < 8; ++z) acc[z] += m * bf2f(u[z]);
        }
        #pragma unroll
        for (int z = 0; z < 8; ++z) acc[z] += __shfl_xor(acc[z], 32);
        if (half == 0) {
            unsigned short o8[8];
            #pragma unroll
            for (int z = 0; z < 8; ++z) o8[z] = f2bf(acc[z]);
            *reinterpret_cast<uint4v*>(&sA[row * SAS + c]) = *reinterpret_cast<uint4v*>(o8);
        }
    }
    __syncthreads();
    int lr = lane & 15, quad = lane >> 4;
    float xp[4][4], bb[4];
    #pragma unroll
    for (int t = 0; t < 4; ++t) {
        int col = (w * 4 + t) * 16 + lr;
        bb[t] = 2.f * b[col];
        #pragma unroll
        for (int r = 0; r < 4; ++r)
            xp[t][r] = bf2f(xh[(size_t)(n0 + quad * 4 + r) * DD + col]);
    }
    floatx4 z = {0.f, 0.f, 0.f, 0.f};
    floatx4 acc[4] = {z, z, z, z};
    for (int kt = 0; kt < 10; ++kt) {
        bf16x8 a = *reinterpret_cast<const bf16x8*>(&sA[lr * SAS + kt * 32 + quad * 8]);
        #pragma unroll
        for (int t = 0; t < 4; ++t) {
            bf16x8 bf = *reinterpret_cast<const bf16x8*>(&U[(size_t)((kt * NT1 + w * 4 + t) * 64 + lane) * 8]);
            acc[t] = __builtin_amdgcn_mfma_f32_16x16x32_bf16(a, bf, acc[t], 0, 0, 0);
        }
    }
    #pragma unroll
    for (int t = 0; t < 4; ++t) {
        int col = (w * 4 + t) * 16 + lr;
        #pragma unroll
        for (int r = 0; r < 4; ++r) {
            size_t o = (size_t)(n0 + quad * 4 + r) * DD + col;
            float v = xp[t][r] + bb[t] + acc[t][r];
            out[o] = v;
            h8[o] = f2q(v);
        }
    }
}

// Fused pass 2 (R5-proven): fp8 gather of hidden into bf16 LDS A-tile, then BOTH
// mu and logvar bf16 matmuls + fast tanh + KLD atomically accumulated.
__global__ __launch_bounds__(256) void fmm23(const unsigned char* __restrict__ h8, const unsigned short* __restrict__ Hc,
                                             const int* __restrict__ ii, const float* __restrict__ im,
                                             const int* __restrict__ oi, const float* __restrict__ om,
                                             const unsigned short* __restrict__ U, const float* __restrict__ b2,
                                             const float* __restrict__ b3, float* __restrict__ kld) {
    __shared__ unsigned short sA[16 * SAS];
    __shared__ int sidx[16][32];
    __shared__ float smsk[16][32];
    __shared__ float red[4];
    int n0 = blockIdx.x * 16;
    int tid = threadIdx.x;
    for (int q = tid; q < 512; q += 256) {
        int r = q >> 5, j = q & 31;
        int n = n0 + r;
        sidx[r][j] = (j < 16) ? ii[n * KK + j] : oi[n * KK + j - 16];
        smsk[r][j] = (j < 16) ? im[n * KK + j] : om[n * KK + j - 16];
    }
    if (tid < 128) {
        int r = tid >> 3, k8 = tid & 7;
        *reinterpret_cast<uint4v*>(&sA[r * SAS + 256 + k8 * 8]) =
            *reinterpret_cast<const uint4v*>(&Hc[(size_t)(n0 + r) * 64 + k8 * 8]);
    }
    __syncthreads();
    int lane = tid & 63, w = tid >> 6;
    int g = lane >> 4, cl = lane & 15;
    #pragma unroll
    for (int rr = 0; rr < 4; ++rr) {
        int row = w * 4 + rr;
        float acc[16];
        #pragma unroll
        for (int z = 0; z < 16; ++z) acc[z] = 0.f;
        #pragma unroll
        for (int j = 0; j < 8; ++j) {
            int r = g * 8 + j;
            int idx = sidx[row][r];
            float m = smsk[row][r];
            uint4v u = *reinterpret_cast<const uint4v*>(h8 + (size_t)idx * DD + cl * 16);
            #pragma unroll
            for (int d = 0; d < 4; ++d) {
                floatx2 f01 = __builtin_amdgcn_cvt_pk_f32_fp8(u[d], false);
                floatx2 f23 = __builtin_amdgcn_cvt_pk_f32_fp8(u[d], true);
                acc[d * 4 + 0] += m * f01.x; acc[d * 4 + 1] += m * f01.y;
                acc[d * 4 + 2] += m * f23.x; acc[d * 4 + 3] += m * f23.y;
            }
        }
        #pragma unroll
        for (int z = 0; z < 16; ++z) {
            acc[z] += __shfl_xor(acc[z], 16);
            acc[z] += __shfl_xor(acc[z], 32);
        }
        if (g == 0) {
            unsigned short o16[16];
            #pragma unroll
            for (int z = 0; z < 16; ++z) o16[z] = f2bf(acc[z]);
            uint4v* dst = reinterpret_cast<uint4v*>(&sA[row * SAS + cl * 16]);
            dst[0] = reinterpret_cast<uint4v*>(o16)[0];
            dst[1] = reinterpret_cast<uint4v*>(o16)[1];
        }
    }
    __syncthreads();
    int lr = lane & 15, quad = lane >> 4;
    float hp[4][4], bm[4], bl[4];
    #pragma unroll
    for (int t = 0; t < 4; ++t) {
        int col = (w * 4 + t) * 16 + lr;
        bm[t] = 2.f * b2[col];
        bl[t] = 2.f * b3[col];
        #pragma unroll
        for (int r = 0; r < 4; ++r)
            hp[t][r] = q2f(h8[(size_t)(n0 + quad * 4 + r) * DD + col]);
    }
    floatx4 z = {0.f, 0.f, 0.f, 0.f};
    floatx4 am[4] = {z, z, z, z};
    floatx4 al[4] = {z, z, z, z};
    for (int kt = 0; kt < 10; ++kt) {
        bf16x8 a = *reinterpret_cast<const bf16x8*>(&sA[lr * SAS + kt * 32 + quad * 8]);
        #pragma unroll
        for (int t = 0; t < 4; ++t) {
            int nt = w * 4 + t;
            bf16x8 bmu = *reinterpret_cast<const bf16x8*>(&U[(size_t)((kt * 32 + nt) * 64 + lane) * 8]);
            bf16x8 blv = *reinterpret_cast<const bf16x8*>(&U[(size_t)((kt * 32 + 16 + nt) * 64 + lane) * 8]);
            am[t] = __builtin_amdgcn_mfma_f32_16x16x32_bf16(a, bmu, am[t], 0, 0, 0);
            al[t] = __builtin_amdgcn_mfma_f32_16x16x32_bf16(a, blv, al[t], 0, 0, 0);
        }
    }
    float kacc = 0.f;
    #pragma unroll
    for (int t = 0; t < 4; ++t) {
        #pragma unroll
        for (int r = 0; r < 4; ++r) {
            float h = hp[t][r];
            float tm = ftanh(h + bm[t] + am[t][r]);
            float tl = ftanh(h + bl[t] + al[t][r]);
            kacc += (1.f - tm * tm) + (2.f * tl - __expf(2.f * tl));
        }
    }
    #pragma unroll
    for (int off = 32; off > 0; off >>= 1) kacc += __shfl_xor(kacc, off);
    if (lane == 0) red[w] = kacc;
    __syncthreads();
    if (tid == 0)
        atomicAdd(kld, (red[0] + red[1] + red[2] + red[3]) * (-0.5f / ((float)NN * (float)NN)));
}

extern "C" void kernel_launch(void* const* d_in, const int* in_sizes, int n_in,
                              void* d_out, int out_size, void* d_ws, size_t ws_size,
                              hipStream_t stream) {
    const float* x  = (const float*)d_in[0];
    const int*   ii = (const int*)d_in[1];
    const int*   ie = (const int*)d_in[2];
    const float* im = (const float*)d_in[3];
    const int*   oi = (const int*)d_in[4];
    const int*   oe = (const int*)d_in[5];
    const float* om = (const float*)d_in[6];
    const float* e1 = (const float*)d_in[7];
    const float* W1 = (const float*)d_in[8];
    const float* b1 = (const float*)d_in[9];
    const float* e2 = (const float*)d_in[10];
    const float* W2 = (const float*)d_in[11];
    const float* b2 = (const float*)d_in[12];
    const float* e3 = (const float*)d_in[13];
    const float* W3 = (const float*)d_in[14];
    const float* b3 = (const float*)d_in[15];
    float* out = (float*)d_out;
    float* kld = out + (size_t)NN * DD;

    char* ws = (char*)d_ws;
    float*          EW  = (float*)(ws);                     // 3*64*256 f32    (196608 B)
    unsigned short* U1  = (unsigned short*)(ws + 196608);   // 163840 B
    unsigned short* U23 = (unsigned short*)(ws + 360448);   // 327680 B
    unsigned short* Hc  = (unsigned short*)(ws + 688128);   // 20000*64 bf16   (2.56 MB)
    unsigned short* xh  = (unsigned short*)(ws + 3248128);  // 20000*256 bf16  (10.24 MB)
    unsigned char*  h8  = (unsigned char*)(ws + 13488128);  // 20000*256 fp8   (5.12 MB)

    ewhist<<<192 + NN / 4, 256, 0, stream>>>(ie, im, oe, om, x, e1, W1, e2, W2, e3, W3,
                                             EW, Hc, xh, kld);
    packU <<<120, 256, 0, stream>>>(W1, W2, W3, EW, U1, U23);
    fmm1  <<<NN / 16, 256, 0, stream>>>(xh, Hc, ii, im, oi, om, U1, b1, out, h8);
    fmm23 <<<NN / 16, 256, 0, stream>>>(h8, Hc, ii, im, oi, om, U23, b2, b3, kld);
}